// Round 1
// baseline (1589.410 us; speedup 1.0000x reference)
//
#include <hip/hip_runtime.h>

#define DMODEL 128

// ---------------- degree / dinv ----------------
__global__ void deg_kernel(const int* __restrict__ dst, float* __restrict__ deg, int E) {
    int e = blockIdx.x * blockDim.x + threadIdx.x;
    if (e < E) atomicAdd(&deg[dst[e]], 1.0f);
}

__global__ void dinv_kernel(float* __restrict__ deg, int n) {
    int i = blockIdx.x * blockDim.x + threadIdx.x;
    if (i < n) deg[i] = rsqrtf(deg[i] + 1.0f);
}

// ---------------- GEMM: C[n,128] = A[n,128] * W[128,128] ----------------
// grid.x = ceil(n/64) row blocks, grid.y = 2 (64-col halves). 256 threads.
// LDS: A-tile transposed [k][r] + W-tile [k][c], 32KB each -> 2 blocks/CU.
__global__ __launch_bounds__(256) void gemm_kernel(const float* __restrict__ A,
                                                   const float* __restrict__ W,
                                                   float* __restrict__ C, int n) {
    __shared__ float sA[128][64];   // [k][r]
    __shared__ float sW[128][64];   // [k][c]
    const int tid  = threadIdx.x;
    const int row0 = blockIdx.x * 64;
    const int col0 = blockIdx.y * 64;

    // stage A (64 rows x 128 k), transpose into sA[k][r]; r = lane for
    // conflict-free LDS writes, float4 global reads.
    for (int t = tid; t < 64 * 32; t += 256) {
        int r  = t & 63;        // row within tile
        int k4 = t >> 6;        // float4 index along k, 0..31
        int row = row0 + r;
        float4 v = make_float4(0.f, 0.f, 0.f, 0.f);
        if (row < n) v = *(const float4*)&A[(size_t)row * DMODEL + k4 * 4];
        sA[k4 * 4 + 0][r] = v.x;
        sA[k4 * 4 + 1][r] = v.y;
        sA[k4 * 4 + 2][r] = v.z;
        sA[k4 * 4 + 3][r] = v.w;
    }
    // stage W rows k=0..127, cols col0..col0+63 (contiguous float4 copies)
    for (int t = tid; t < 128 * 16; t += 256) {
        int k  = t >> 4;
        int c4 = t & 15;
        *(float4*)&sW[k][c4 * 4] = *(const float4*)&W[k * DMODEL + col0 + c4 * 4];
    }
    __syncthreads();

    const int tx = tid & 15;    // col group (4 cols)
    const int ty = tid >> 4;    // row group (4 rows)
    float acc[4][4] = {};
#pragma unroll 8
    for (int k = 0; k < 128; ++k) {
        float4 a = *(const float4*)&sA[k][ty * 4];
        float4 w = *(const float4*)&sW[k][tx * 4];
        float av[4] = {a.x, a.y, a.z, a.w};
        float wv[4] = {w.x, w.y, w.z, w.w};
#pragma unroll
        for (int i = 0; i < 4; ++i)
#pragma unroll
            for (int j = 0; j < 4; ++j)
                acc[i][j] += av[i] * wv[j];
    }
#pragma unroll
    for (int i = 0; i < 4; ++i) {
        int row = row0 + ty * 4 + i;
        if (row < n) {
            *(float4*)&C[(size_t)row * DMODEL + col0 + tx * 4] =
                make_float4(acc[i][0], acc[i][1], acc[i][2], acc[i][3]);
        }
    }
}

// ---------------- edge scatter: agg[dst] += hw[src] * dinv[src]*dinv[dst] ----------------
// 2 edges per 256-thread block; one thread per (edge, channel).
__global__ void scatter_kernel(const float* __restrict__ hw, const int* __restrict__ src,
                               const int* __restrict__ dst, const float* __restrict__ dinv,
                               float* __restrict__ agg, int E) {
    int e = blockIdx.x * 2 + (threadIdx.x >> 7);
    int c = threadIdx.x & 127;
    if (e < E) {
        int s = src[e];
        int d = dst[e];
        float norm = dinv[s] * dinv[d];
        atomicAdd(&agg[(size_t)d * DMODEL + c], hw[(size_t)s * DMODEL + c] * norm);
    }
}

// ---------------- layer-1 epilogue: h = relu(agg + hw*dinv^2 + b) (in place in agg) ------
__global__ void selfloop_relu_kernel(float* __restrict__ agg, const float* __restrict__ hw,
                                     const float* __restrict__ dinv, const float* __restrict__ b,
                                     int n) {
    long long idx = (long long)blockIdx.x * blockDim.x + threadIdx.x;
    if (idx < (long long)n * DMODEL) {
        int i = (int)(idx >> 7);
        int c = (int)(idx & 127);
        float di = dinv[i];
        float v = agg[idx] + hw[idx] * di * di + b[c];
        agg[idx] = fmaxf(v, 0.f);
    }
}

// ---------------- layer-2 epilogue: out = agg + hw*dinv^2 + b, duplicated to both halves -
__global__ void final_kernel(float* __restrict__ out, const float* __restrict__ hw,
                             const float* __restrict__ dinv, const float* __restrict__ b,
                             int n) {
    long long idx = (long long)blockIdx.x * blockDim.x + threadIdx.x;
    long long tot = (long long)n * DMODEL;
    if (idx < tot) {
        int i = (int)(idx >> 7);
        int c = (int)(idx & 127);
        float di = dinv[i];
        float v = out[idx] + hw[idx] * di * di + b[c];
        out[idx] = v;
        out[tot + idx] = v;
    }
}

extern "C" void kernel_launch(void* const* d_in, const int* in_sizes, int n_in,
                              void* d_out, int out_size, void* d_ws, size_t ws_size,
                              hipStream_t stream) {
    const float* x  = (const float*)d_in[0];
    const int*   ei = (const int*)d_in[1];
    const float* W1 = (const float*)d_in[2];
    const float* b1 = (const float*)d_in[3];
    const float* W2 = (const float*)d_in[4];
    const float* b2 = (const float*)d_in[5];
    float* out = (float*)d_out;

    const int n = in_sizes[0] / DMODEL;       // 169343
    const int E = in_sizes[1] / 2;            // 1166243
    const int* src = ei;
    const int* dst = ei + E;

    const long long nd = (long long)n * DMODEL;

    // workspace: dinv (N floats) + hw buffer (N*128 floats)
    float* dinv = (float*)d_ws;
    float* hw   = dinv + ((n + 255) / 256) * 256;   // aligned

    // layer-1 aggregate / h lives in the SECOND half of d_out (rewritten at the end)
    float* agg1 = out + nd;

    // zero accumulators (d_out/d_ws are poisoned 0xAA before every launch)
    hipMemsetAsync(dinv, 0, n * sizeof(float), stream);
    hipMemsetAsync(out, 0, (size_t)out_size * sizeof(float), stream);

    deg_kernel<<<(E + 255) / 256, 256, 0, stream>>>(dst, dinv, E);
    dinv_kernel<<<(n + 255) / 256, 256, 0, stream>>>(dinv, n);

    dim3 ggrid((n + 63) / 64, 2);

    // layer 1
    gemm_kernel<<<ggrid, 256, 0, stream>>>(x, W1, hw, n);
    scatter_kernel<<<(E + 1) / 2, 256, 0, stream>>>(hw, src, dst, dinv, agg1, E);
    selfloop_relu_kernel<<<(int)((nd + 255) / 256), 256, 0, stream>>>(agg1, hw, dinv, b1, n);

    // layer 2 (h == agg1)
    gemm_kernel<<<ggrid, 256, 0, stream>>>(agg1, W2, hw, n);
    scatter_kernel<<<(E + 1) / 2, 256, 0, stream>>>(hw, src, dst, dinv, out, E);
    final_kernel<<<(int)((nd + 255) / 256), 256, 0, stream>>>(out, hw, dinv, b2, n);
}

// Round 2
// 852.833 us; speedup vs baseline: 1.8637x; 1.8637x over previous
//
#include <hip/hip_runtime.h>

#define DMODEL 128

// ================= CSR build =================
__global__ void cnt_kernel(const int* __restrict__ dst, int* __restrict__ cnt, int E) {
    int e = blockIdx.x * blockDim.x + threadIdx.x;
    if (e < E) atomicAdd(&cnt[dst[e]], 1);
}

// inclusive scan within 256-blocks + block totals
__global__ void scan1_kernel(const int* __restrict__ cnt, int* __restrict__ incl,
                             int* __restrict__ bsum, int n) {
    __shared__ int s[256];
    int t = threadIdx.x;
    int i = blockIdx.x * 256 + t;
    int v = (i < n) ? cnt[i] : 0;
    s[t] = v;
    __syncthreads();
    for (int off = 1; off < 256; off <<= 1) {
        int add = (t >= off) ? s[t - off] : 0;
        __syncthreads();
        s[t] += add;
        __syncthreads();
    }
    if (i < n) incl[i] = s[t];
    if (t == 255) bsum[blockIdx.x] = s[255];
}

// single-block exclusive scan of block sums (in place)
__global__ void scan2_kernel(int* __restrict__ bsum, int nb) {
    __shared__ int s[256];
    __shared__ int carry;
    int t = threadIdx.x;
    if (t == 0) carry = 0;
    __syncthreads();
    for (int base = 0; base < nb; base += 256) {
        int idx = base + t;
        int v = (idx < nb) ? bsum[idx] : 0;
        s[t] = v;
        __syncthreads();
        for (int off = 1; off < 256; off <<= 1) {
            int add = (t >= off) ? s[t - off] : 0;
            __syncthreads();
            s[t] += add;
            __syncthreads();
        }
        int excl = carry + s[t] - v;
        if (idx < nb) bsum[idx] = excl;
        __syncthreads();                 // all threads have read carry
        if (t == 255) carry += s[255];   // chunk total
        // next iteration's __syncthreads() makes the update visible
    }
}

// offsets/cursor/dinv from scan pieces
__global__ void scan3_kernel(const int* __restrict__ cnt, const int* __restrict__ incl,
                             const int* __restrict__ bsum, int* __restrict__ offsets,
                             int* __restrict__ cursor, float* __restrict__ dinv,
                             int n, int E) {
    int i = blockIdx.x * 256 + threadIdx.x;
    if (i < n) {
        int v = cnt[i];
        int excl = incl[i] - v + bsum[blockIdx.x];
        offsets[i] = excl;
        cursor[i] = excl;
        dinv[i] = rsqrtf((float)v + 1.0f);
    }
    if (i == 0) offsets[n] = E;
}

__global__ void fill_kernel(const int* __restrict__ src, const int* __restrict__ dst,
                            int* __restrict__ cursor, int* __restrict__ srcs, int E) {
    int e = blockIdx.x * blockDim.x + threadIdx.x;
    if (e < E) {
        int p = atomicAdd(&cursor[dst[e]], 1);
        srcs[p] = src[e];
    }
}

// ================= GEMM: C[n,128] = A[n,128] * W[128,128] =================
__global__ __launch_bounds__(256) void gemm_kernel(const float* __restrict__ A,
                                                   const float* __restrict__ W,
                                                   float* __restrict__ C, int n) {
    __shared__ float sA[128][64];   // [k][r]
    __shared__ float sW[128][64];   // [k][c]
    const int tid  = threadIdx.x;
    const int row0 = blockIdx.x * 64;
    const int col0 = blockIdx.y * 64;

    for (int t = tid; t < 64 * 32; t += 256) {
        int r  = t & 63;
        int k4 = t >> 6;
        int row = row0 + r;
        float4 v = make_float4(0.f, 0.f, 0.f, 0.f);
        if (row < n) v = *(const float4*)&A[(size_t)row * DMODEL + k4 * 4];
        sA[k4 * 4 + 0][r] = v.x;
        sA[k4 * 4 + 1][r] = v.y;
        sA[k4 * 4 + 2][r] = v.z;
        sA[k4 * 4 + 3][r] = v.w;
    }
    for (int t = tid; t < 128 * 16; t += 256) {
        int k  = t >> 4;
        int c4 = t & 15;
        *(float4*)&sW[k][c4 * 4] = *(const float4*)&W[k * DMODEL + col0 + c4 * 4];
    }
    __syncthreads();

    const int tx = tid & 15;
    const int ty = tid >> 4;
    float acc[4][4] = {};
#pragma unroll 8
    for (int k = 0; k < 128; ++k) {
        float4 a = *(const float4*)&sA[k][ty * 4];
        float4 w = *(const float4*)&sW[k][tx * 4];
        float av[4] = {a.x, a.y, a.z, a.w};
        float wv[4] = {w.x, w.y, w.z, w.w};
#pragma unroll
        for (int i = 0; i < 4; ++i)
#pragma unroll
            for (int j = 0; j < 4; ++j)
                acc[i][j] += av[i] * wv[j];
    }
#pragma unroll
    for (int i = 0; i < 4; ++i) {
        int row = row0 + ty * 4 + i;
        if (row < n) {
            *(float4*)&C[(size_t)row * DMODEL + col0 + tx * 4] =
                make_float4(acc[i][0], acc[i][1], acc[i][2], acc[i][3]);
        }
    }
}

// ================= pull aggregation (fused self-loop + bias + relu) =================
// one 64-lane wave per node; each lane owns 2 channels (float2 = 512B/row coalesced)
__global__ __launch_bounds__(256) void pull_kernel(const float* __restrict__ hw,
                                                   const int* __restrict__ offsets,
                                                   const int* __restrict__ srcs,
                                                   const float* __restrict__ dinv,
                                                   const float* __restrict__ bias,
                                                   float* __restrict__ outp,
                                                   int n, int relu) {
    int node = blockIdx.x * 4 + (threadIdx.x >> 6);
    int lane = threadIdx.x & 63;
    if (node >= n) return;
    const float2* hwv = (const float2*)hw;
    float di = dinv[node];
    int c = lane * 2;
    float2 selfv = hwv[(size_t)node * 64 + lane];
    float s2 = di * di;
    float2 acc;
    acc.x = selfv.x * s2 + bias[c];
    acc.y = selfv.y * s2 + bias[c + 1];
    int e0 = offsets[node];
    int e1 = offsets[node + 1];
    for (int e = e0; e < e1; ++e) {
        int s = srcs[e];
        float w = dinv[s] * di;
        float2 v = hwv[(size_t)s * 64 + lane];
        acc.x += v.x * w;
        acc.y += v.y * w;
    }
    if (relu) {
        acc.x = fmaxf(acc.x, 0.f);
        acc.y = fmaxf(acc.y, 0.f);
    }
    ((float2*)outp)[(size_t)node * 64 + lane] = acc;
}

// duplicate result into both output halves
__global__ void dup_kernel(const float4* __restrict__ s, float4* __restrict__ a,
                           float4* __restrict__ b, int n4) {
    int i = blockIdx.x * blockDim.x + threadIdx.x;
    if (i < n4) {
        float4 v = s[i];
        a[i] = v;
        b[i] = v;
    }
}

extern "C" void kernel_launch(void* const* d_in, const int* in_sizes, int n_in,
                              void* d_out, int out_size, void* d_ws, size_t ws_size,
                              hipStream_t stream) {
    const float* x  = (const float*)d_in[0];
    const int*   ei = (const int*)d_in[1];
    const float* W1 = (const float*)d_in[2];
    const float* b1 = (const float*)d_in[3];
    const float* W2 = (const float*)d_in[4];
    const float* b2 = (const float*)d_in[5];
    float* out = (float*)d_out;

    const int n = in_sizes[0] / DMODEL;     // 169343
    const int E = in_sizes[1] / 2;          // 1166243
    const int* src = ei;
    const int* dst = ei + E;

    const long long nd = (long long)n * DMODEL;
    const int NB = (n + 255) / 256;
    const int Na = NB * 256;                // n rounded up to 256

    // ---- d_ws: dinv + hw buffer (proven footprint from R1) ----
    float* dinv = (float*)d_ws;
    float* hwbuf = dinv + (((n + 255) / 256) * 256);   // h / final result buffer

    // ---- CSR scratch lives in out[0:nd] (overwritten by dup at the end) ----
    int* cnt     = (int*)out;                       // N
    int* incl    = cnt + Na;                        // N
    int* bsum    = incl + Na;                       // NB
    int* offsets = bsum + ((NB + 255) / 256) * 256; // N+1
    int* cursor  = offsets + Na + 256;              // N
    int* srcs    = cursor + Na;                     // E

    float* outA = out;            // first half (CSR scratch until the end)
    float* outB = out + nd;       // second half (hw ping buffer)

    // ---- build CSR (sorted-by-dst adjacency) ----
    hipMemsetAsync(cnt, 0, (size_t)n * sizeof(int), stream);
    cnt_kernel<<<(E + 255) / 256, 256, 0, stream>>>(dst, cnt, E);
    scan1_kernel<<<NB, 256, 0, stream>>>(cnt, incl, bsum, n);
    scan2_kernel<<<1, 256, 0, stream>>>(bsum, NB);
    scan3_kernel<<<NB, 256, 0, stream>>>(cnt, incl, bsum, offsets, cursor, dinv, n, E);
    fill_kernel<<<(E + 255) / 256, 256, 0, stream>>>(src, dst, cursor, srcs, E);

    dim3 ggrid((n + 63) / 64, 2);
    const int pull_grid = (n + 3) / 4;

    // ---- layer 1: hw1 = x@W1 -> outB; h = relu(agg) -> hwbuf ----
    gemm_kernel<<<ggrid, 256, 0, stream>>>(x, W1, outB, n);
    pull_kernel<<<pull_grid, 256, 0, stream>>>(outB, offsets, srcs, dinv, b1, hwbuf, n, 1);

    // ---- layer 2: hw2 = h@W2 -> outB; out = agg -> hwbuf ----
    gemm_kernel<<<ggrid, 256, 0, stream>>>(hwbuf, W2, outB, n);
    pull_kernel<<<pull_grid, 256, 0, stream>>>(outB, offsets, srcs, dinv, b2, hwbuf, n, 0);

    // ---- fan out to both halves of d_out ----
    const int n4 = (int)(nd / 4);
    dup_kernel<<<(n4 + 255) / 256, 256, 0, stream>>>((const float4*)hwbuf,
                                                     (float4*)outA, (float4*)outB, n4);
}

// Round 3
// 726.254 us; speedup vs baseline: 2.1885x; 1.1743x over previous
//
#include <hip/hip_runtime.h>

#define DMODEL 128

// ================= CSR build =================
__global__ void cnt_kernel(const int* __restrict__ dst, int* __restrict__ cnt, int E) {
    int e = blockIdx.x * blockDim.x + threadIdx.x;
    if (e < E) atomicAdd(&cnt[dst[e]], 1);
}

// inclusive scan within 256-blocks + block totals
__global__ void scan1_kernel(const int* __restrict__ cnt, int* __restrict__ incl,
                             int* __restrict__ bsum, int n) {
    __shared__ int s[256];
    int t = threadIdx.x;
    int i = blockIdx.x * 256 + t;
    int v = (i < n) ? cnt[i] : 0;
    s[t] = v;
    __syncthreads();
    for (int off = 1; off < 256; off <<= 1) {
        int add = (t >= off) ? s[t - off] : 0;
        __syncthreads();
        s[t] += add;
        __syncthreads();
    }
    if (i < n) incl[i] = s[t];
    if (t == 255) bsum[blockIdx.x] = s[255];
}

// single-block exclusive scan of block sums (in place)
__global__ void scan2_kernel(int* __restrict__ bsum, int nb) {
    __shared__ int s[256];
    __shared__ int carry;
    int t = threadIdx.x;
    if (t == 0) carry = 0;
    __syncthreads();
    for (int base = 0; base < nb; base += 256) {
        int idx = base + t;
        int v = (idx < nb) ? bsum[idx] : 0;
        s[t] = v;
        __syncthreads();
        for (int off = 1; off < 256; off <<= 1) {
            int add = (t >= off) ? s[t - off] : 0;
            __syncthreads();
            s[t] += add;
            __syncthreads();
        }
        int excl = carry + s[t] - v;
        if (idx < nb) bsum[idx] = excl;
        __syncthreads();
        if (t == 255) carry += s[255];
    }
}

// offsets/cursor/dinv from scan pieces
__global__ void scan3_kernel(const int* __restrict__ cnt, const int* __restrict__ incl,
                             const int* __restrict__ bsum, int* __restrict__ offsets,
                             int* __restrict__ cursor, float* __restrict__ dinv,
                             int n, int E) {
    int i = blockIdx.x * 256 + threadIdx.x;
    if (i < n) {
        int v = cnt[i];
        int excl = incl[i] - v + bsum[blockIdx.x];
        offsets[i] = excl;
        cursor[i] = excl;
        dinv[i] = rsqrtf((float)v + 1.0f);
    }
    if (i == 0) offsets[n] = E;
}

// counting-sort fill of packed edge records {src, w = dinv[src]*dinv[dst]}
__global__ void fill_kernel(const int* __restrict__ src, const int* __restrict__ dst,
                            int* __restrict__ cursor, const float* __restrict__ dinv,
                            int2* __restrict__ er, int E) {
    int e = blockIdx.x * blockDim.x + threadIdx.x;
    if (e < E) {
        int s = src[e];
        int d = dst[e];
        int p = atomicAdd(&cursor[d], 1);
        er[p] = make_int2(s, __float_as_int(dinv[s] * dinv[d]));
    }
}

// ================= GEMM: C[n,128] = A[n,128] * W[128,128] =================
__global__ __launch_bounds__(256) void gemm_kernel(const float* __restrict__ A,
                                                   const float* __restrict__ W,
                                                   float* __restrict__ C, int n) {
    __shared__ float sA[128][64];   // [k][r]
    __shared__ float sW[128][64];   // [k][c]
    const int tid  = threadIdx.x;
    const int row0 = blockIdx.x * 64;
    const int col0 = blockIdx.y * 64;

    for (int t = tid; t < 64 * 32; t += 256) {
        int r  = t & 63;
        int k4 = t >> 6;
        int row = row0 + r;
        float4 v = make_float4(0.f, 0.f, 0.f, 0.f);
        if (row < n) v = *(const float4*)&A[(size_t)row * DMODEL + k4 * 4];
        sA[k4 * 4 + 0][r] = v.x;
        sA[k4 * 4 + 1][r] = v.y;
        sA[k4 * 4 + 2][r] = v.z;
        sA[k4 * 4 + 3][r] = v.w;
    }
    for (int t = tid; t < 128 * 16; t += 256) {
        int k  = t >> 4;
        int c4 = t & 15;
        *(float4*)&sW[k][c4 * 4] = *(const float4*)&W[k * DMODEL + col0 + c4 * 4];
    }
    __syncthreads();

    const int tx = tid & 15;
    const int ty = tid >> 4;
    float acc[4][4] = {};
#pragma unroll 8
    for (int k = 0; k < 128; ++k) {
        float4 a = *(const float4*)&sA[k][ty * 4];
        float4 w = *(const float4*)&sW[k][tx * 4];
        float av[4] = {a.x, a.y, a.z, a.w};
        float wv[4] = {w.x, w.y, w.z, w.w};
#pragma unroll
        for (int i = 0; i < 4; ++i)
#pragma unroll
            for (int j = 0; j < 4; ++j)
                acc[i][j] += av[i] * wv[j];
    }
#pragma unroll
    for (int i = 0; i < 4; ++i) {
        int row = row0 + ty * 4 + i;
        if (row < n) {
            *(float4*)&C[(size_t)row * DMODEL + col0 + tx * 4] =
                make_float4(acc[i][0], acc[i][1], acc[i][2], acc[i][3]);
        }
    }
}

// ================= pull aggregation (fused self-loop + bias + relu) =================
// one 64-lane wave per node; lane owns 2 channels; 4-way unrolled edge loop
// (4 independent 512B row-gathers in flight per wave).
__global__ __launch_bounds__(256) void pull_kernel(const float* __restrict__ hw,
                                                   const int* __restrict__ offsets,
                                                   const int2* __restrict__ er,
                                                   const float* __restrict__ dinv,
                                                   const float* __restrict__ bias,
                                                   float* __restrict__ out1,
                                                   float* __restrict__ out2,
                                                   int n, int relu) {
    int node = blockIdx.x * 4 + (threadIdx.x >> 6);
    int lane = threadIdx.x & 63;
    if (node >= n) return;
    const float2* hwv = (const float2*)hw;
    float di = dinv[node];
    float s2 = di * di;
    float2 selfv = hwv[(size_t)node * 64 + lane];
    float2 a0, a1, a2, a3;
    a0.x = selfv.x * s2 + bias[lane * 2];
    a0.y = selfv.y * s2 + bias[lane * 2 + 1];
    a1 = make_float2(0.f, 0.f);
    a2 = make_float2(0.f, 0.f);
    a3 = make_float2(0.f, 0.f);
    int e0 = offsets[node];
    int e1 = offsets[node + 1];
    int e = e0;
    for (; e + 4 <= e1; e += 4) {
        int2 r0 = er[e];
        int2 r1 = er[e + 1];
        int2 r2 = er[e + 2];
        int2 r3 = er[e + 3];
        float2 v0 = hwv[(size_t)r0.x * 64 + lane];
        float2 v1 = hwv[(size_t)r1.x * 64 + lane];
        float2 v2 = hwv[(size_t)r2.x * 64 + lane];
        float2 v3 = hwv[(size_t)r3.x * 64 + lane];
        float w0 = __int_as_float(r0.y);
        float w1 = __int_as_float(r1.y);
        float w2 = __int_as_float(r2.y);
        float w3 = __int_as_float(r3.y);
        a0.x += v0.x * w0; a0.y += v0.y * w0;
        a1.x += v1.x * w1; a1.y += v1.y * w1;
        a2.x += v2.x * w2; a2.y += v2.y * w2;
        a3.x += v3.x * w3; a3.y += v3.y * w3;
    }
    for (; e < e1; ++e) {
        int2 r = er[e];
        float w = __int_as_float(r.y);
        float2 v = hwv[(size_t)r.x * 64 + lane];
        a0.x += v.x * w;
        a0.y += v.y * w;
    }
    float2 acc;
    acc.x = (a0.x + a1.x) + (a2.x + a3.x);
    acc.y = (a0.y + a1.y) + (a2.y + a3.y);
    if (relu) {
        acc.x = fmaxf(acc.x, 0.f);
        acc.y = fmaxf(acc.y, 0.f);
    }
    ((float2*)out1)[(size_t)node * 64 + lane] = acc;
    if (out2) ((float2*)out2)[(size_t)node * 64 + lane] = acc;
}

// duplicate result into both output halves (fallback path only)
__global__ void dup_kernel(const float4* __restrict__ s, float4* __restrict__ a,
                           float4* __restrict__ b, int n4) {
    int i = blockIdx.x * blockDim.x + threadIdx.x;
    if (i < n4) {
        float4 v = s[i];
        a[i] = v;
        b[i] = v;
    }
}

extern "C" void kernel_launch(void* const* d_in, const int* in_sizes, int n_in,
                              void* d_out, int out_size, void* d_ws, size_t ws_size,
                              hipStream_t stream) {
    const float* x  = (const float*)d_in[0];
    const int*   ei = (const int*)d_in[1];
    const float* W1 = (const float*)d_in[2];
    const float* b1 = (const float*)d_in[3];
    const float* W2 = (const float*)d_in[4];
    const float* b2 = (const float*)d_in[5];
    float* out = (float*)d_out;

    const int n = in_sizes[0] / DMODEL;     // 169343
    const int E = in_sizes[1] / 2;          // 1166243
    const int* src = ei;
    const int* dst = ei + E;

    const long long nd = (long long)n * DMODEL;
    const int NB = (n + 255) / 256;
    const int Na = NB * 256;
    const int NBa = ((NB + 255) / 256) * 256;
    const int Ea = ((E + 255) / 256) * 256;

    float* outA = out;
    float* outB = out + nd;

    // ---- d_ws base: dinv + hw ping buffer ----
    float* dinv  = (float*)d_ws;
    float* hwbuf = dinv + Na;

    // CSR arrays: primary = in d_ws (after hwbuf); fallback = in outA region.
    // needed ws ints: Na(dinv) + nd(hwbuf) + 4*Na + NBa + 256 + 2*Ea
    const size_t need_ints = (size_t)Na + (size_t)nd + 4ull * Na + NBa + 256 + 2ull * Ea;
    const bool ws_csr = ws_size >= need_ints * sizeof(int);

    int* base = ws_csr ? (int*)(hwbuf + nd) : (int*)outA;
    int* cnt     = base;                    // Na
    int* incl    = cnt + Na;                // Na
    int* bsum    = incl + Na;               // NBa
    int* offsets = bsum + NBa;              // Na + 256
    int* cursor  = offsets + Na + 256;      // Na
    int2* er     = (int2*)(cursor + Na);    // E records (8B aligned: all counts are x256)

    // ---- build CSR (sorted-by-dst packed edge records) ----
    hipMemsetAsync(cnt, 0, (size_t)n * sizeof(int), stream);
    cnt_kernel<<<(E + 255) / 256, 256, 0, stream>>>(dst, cnt, E);
    scan1_kernel<<<NB, 256, 0, stream>>>(cnt, incl, bsum, n);
    scan2_kernel<<<1, 256, 0, stream>>>(bsum, NB);
    scan3_kernel<<<NB, 256, 0, stream>>>(cnt, incl, bsum, offsets, cursor, dinv, n, E);
    fill_kernel<<<(E + 255) / 256, 256, 0, stream>>>(src, dst, cursor, dinv, er, E);

    dim3 ggrid((n + 63) / 64, 2);
    const int pull_grid = (n + 3) / 4;

    if (ws_csr) {
        // layer 1: hw1 = x@W1 -> hwbuf; h = relu(agg) -> outB
        gemm_kernel<<<ggrid, 256, 0, stream>>>(x, W1, hwbuf, n);
        pull_kernel<<<pull_grid, 256, 0, stream>>>(hwbuf, offsets, er, dinv, b1,
                                                   outB, nullptr, n, 1);
        // layer 2: hw2 = h@W2 -> hwbuf; out = agg -> both halves directly
        gemm_kernel<<<ggrid, 256, 0, stream>>>(outB, W2, hwbuf, n);
        pull_kernel<<<pull_grid, 256, 0, stream>>>(hwbuf, offsets, er, dinv, b2,
                                                   outA, outB, n, 0);
    } else {
        // fallback (CSR scratch occupies outA until the end)
        gemm_kernel<<<ggrid, 256, 0, stream>>>(x, W1, outB, n);
        pull_kernel<<<pull_grid, 256, 0, stream>>>(outB, offsets, er, dinv, b1,
                                                   hwbuf, nullptr, n, 1);
        gemm_kernel<<<ggrid, 256, 0, stream>>>(hwbuf, W2, outB, n);
        pull_kernel<<<pull_grid, 256, 0, stream>>>(outB, offsets, er, dinv, b2,
                                                   hwbuf, nullptr, n, 0);
        const int n4 = (int)(nd / 4);
        dup_kernel<<<(n4 + 255) / 256, 256, 0, stream>>>((const float4*)hwbuf,
                                                         (float4*)outA, (float4*)outB, n4);
    }
}